// Round 5
// baseline (762.371 us; speedup 1.0000x reference)
//
#include <hip/hip_runtime.h>
#include <hip/hip_bf16.h>
#include <cstdint>

// Problem constants (fixed-shape problem)
constexpr int NT   = 8192;
constexpr int H    = 1024;
constexpr int FFN  = 4096;
constexpr int E    = 8;
constexpr int M    = NT * 2;     // 16384 dispatched rows (topk=2)
constexpr int CAP  = M / E;      // 2048 rows per expert

typedef unsigned short u16;
typedef short short8 __attribute__((ext_vector_type(8)));
typedef float f32x4 __attribute__((ext_vector_type(4)));

constexpr int BS = 130;          // LDS B-tile row stride (u16): 128 + 2 pad
                                 // frag-read bank = (k + n/2)%32 -> 2-way (free)

__device__ __forceinline__ u16 f2bf(float f) {
  union { float f; unsigned u; } c{f};
  unsigned r = (c.u + 0x7FFFu + ((c.u >> 16) & 1u)) >> 16;  // RNE
  return (u16)r;
}
__device__ __forceinline__ float bf2f(u16 u) {
  union { unsigned u; float f; } c{((unsigned)u) << 16};
  return c.f;
}
// async global->LDS direct copy, 16B per lane. LDS dest = wave-uniform base + lane*16.
__device__ __forceinline__ void async16(const void* g, void* l) {
  auto gp = reinterpret_cast<const __attribute__((address_space(1))) unsigned*>(
      reinterpret_cast<uintptr_t>(g));
  auto lp = reinterpret_cast<__attribute__((address_space(3))) unsigned*>(
      reinterpret_cast<uintptr_t>(l));
  __builtin_amdgcn_global_load_lds(gp, lp, 16, 0, 0);
}

// tanh-GELU via sigmoid identity; exp folded into exp2 (coeffs * log2 e).
__device__ __forceinline__ float gelu_fast(float x) {
  const float u = x * x;
  const float w = x * (-2.30220795f + -0.102943895f * u);
  return x * __frcp_rn(1.0f + exp2f(w));
}

// ---------- scatter: 4 tokens per block, 16B stores ----------
__global__ __launch_bounds__(256)
void scatter_kernel(const float* __restrict__ x, const int* __restrict__ sidx,
                    u16* __restrict__ disp) {
  const int b = blockIdx.x;
  const int tid = threadIdx.x;
  const int half = tid >> 7;      // token select within pair
  const int r = tid & 127;        // covers 8 floats each
#pragma unroll
  for (int it = 0; it < 2; ++it) {
    const int t = it * 4096 + b * 2 + half;
    const int r0 = sidx[2 * t + 0];
    const int r1 = sidx[2 * t + 1];
    const float4* xr = (const float4*)(x + (size_t)t * H);
    float4 v0 = xr[r * 2 + 0];
    float4 v1 = xr[r * 2 + 1];
    u16 pk[8] = {f2bf(v0.x), f2bf(v0.y), f2bf(v0.z), f2bf(v0.w),
                 f2bf(v1.x), f2bf(v1.y), f2bf(v1.z), f2bf(v1.w)};
    *(short8*)&disp[(size_t)r0 * H + r * 8] = *(short8*)pk;
    *(short8*)&disp[(size_t)r1 * H + r * 8] = *(short8*)pk;
  }
}

// ---------- GEMM: C[M,N] = A[M,K] * W[K,N], A bf16, W fp32 NATIVE layout ----
// 128x128 tile, BK=64. A staged via async16 (XOR-swizzled chunks, 0 conflicts).
// B staged via VGPR roundtrip: float4 loads -> f2bf -> ds_write_b128 into
// [k][n] LDS tile (stride BS=130 u16); fragments read as 8x ds_read_u16
// (2-way banks = free). expert = b&7 XCD pinning, 4x4 supertile order for L2.
template <bool GELU>
__global__ __launch_bounds__(256)
void gemm_native_kernel(const u16* __restrict__ A,    // [E][Mn][Kn] bf16
                        const float* __restrict__ W,  // [E][Kn][Nn] fp32
                        u16* __restrict__ C,          // [E][Mn][Nn] bf16
                        int Mn, int Nn, int Kn, int ny) {
  __shared__ __align__(16) u16 lA[128 * 64];      // 16384 B
  __shared__ __align__(16) u16 lBT[64 * BS];      // 16640 B

  const int b = blockIdx.x;
  const int e = b & 7;
  const int t = b >> 3;
  const int q = t & 15, s = t >> 4;
  const int sy = ny >> 2;
  const int sm = s % sy, sn = s / sy;
  const int tm = sm * 4 + (q & 3), tn = sn * 4 + (q >> 2);
  const int m0 = tm * 128, n0 = tn * 128;

  const u16*   Ae = A + (size_t)e * Mn * Kn + (size_t)m0 * Kn;
  const float* We = W + (size_t)e * Kn * Nn + n0;
  u16* Ce = C + (size_t)e * Mn * Nn;

  const int tid  = threadIdx.x;
  const int lane = tid & 63;
  const int wave = tid >> 6;
  const int wr = wave >> 1, wc = wave & 1;   // 2x2 wave grid, 64x64 each
  const int lhi = lane >> 4, llo = lane & 15;

  // A staging: inst i covers rows [i*8,i*8+8); lane -> row i*8 + l/8, LDS slot
  // l%8; fetch global chunk (l%8)^(l/8) so A frag reads are conflict-free.
  const int sr = lane >> 3;
  const int gc = (lane & 7) ^ sr;

  // B staging: thread -> (row group k = it*16 + tid/16, n-octet tid%16)
  const int bo = tid & 15;
  const int bk = tid >> 4;

  f32x4 acc[4][4] = {};

  for (int kt = 0; kt < Kn; kt += 64) {
    // ---- A: async global->LDS, 4 insts per wave ----
#pragma unroll
    for (int s2 = 0; s2 < 4; ++s2) {
      const int i = wave * 4 + s2;
      const int row = i * 8 + sr;
      async16(Ae + (size_t)row * Kn + kt + gc * 8, &lA[i * 512]);
    }
    // ---- B: fp32 load -> bf16 -> LDS [k][n] ----
#pragma unroll
    for (int it = 0; it < 4; ++it) {
      const int k = it * 16 + bk;
      const float* src = We + (size_t)(kt + k) * Nn + bo * 8;
      float4 v0 = *(const float4*)src;
      float4 v1 = *(const float4*)(src + 4);
      u16 pk[8] = {f2bf(v0.x), f2bf(v0.y), f2bf(v0.z), f2bf(v0.w),
                   f2bf(v1.x), f2bf(v1.y), f2bf(v1.z), f2bf(v1.w)};
      *(short8*)&lBT[k * BS + bo * 8] = *(short8*)pk;
    }
    __syncthreads();

#pragma unroll 1
    for (int ks = 0; ks < 2; ++ks) {
      short8 af[4], bf[4];
#pragma unroll
      for (int i = 0; i < 4; ++i) {
        const int row = wr * 64 + i * 16 + llo;
        const int pc = (ks * 4 + lhi) ^ (llo & 7);
        af[i] = *(const short8*)&lA[row * 64 + pc * 8];
      }
#pragma unroll
      for (int j = 0; j < 4; ++j) {
        const int n = wc * 64 + j * 16 + llo;
        const int kb = (ks * 4 + lhi) * 8;
        u16 btmp[8];
#pragma unroll
        for (int j2 = 0; j2 < 8; ++j2)
          btmp[j2] = lBT[(kb + j2) * BS + n];
        bf[j] = *(short8*)btmp;
      }
#pragma unroll
      for (int i = 0; i < 4; ++i)
#pragma unroll
        for (int j = 0; j < 4; ++j)
          acc[i][j] = __builtin_amdgcn_mfma_f32_16x16x32_bf16(af[i], bf[j], acc[i][j], 0, 0, 0);
    }
    __syncthreads();
  }

  // epilogue: C/D layout col=lane&15, row=(lane>>4)*4+reg  [m89-verified]
#pragma unroll
  for (int i = 0; i < 4; ++i) {
    const int mrow = m0 + wr * 64 + i * 16 + lhi * 4;
#pragma unroll
    for (int j = 0; j < 4; ++j) {
      const int ncol = n0 + wc * 64 + j * 16 + llo;
#pragma unroll
      for (int r = 0; r < 4; ++r) {
        float v = acc[i][j][r];
        if (GELU) v = gelu_fast(v);
        Ce[(size_t)(mrow + r) * Nn + ncol] = f2bf(v);
      }
    }
  }
}

// ---------- gather + sum topk -> fp32 out; 16B loads, 4 tokens/block --------
__global__ __launch_bounds__(256)
void gather_sum_kernel(const u16* __restrict__ ye,
                       const int* __restrict__ sidx,
                       float* __restrict__ out) {
  const int tid = threadIdx.x;
  const int half = tid >> 7;
  const int r = tid & 127;
#pragma unroll
  for (int it = 0; it < 2; ++it) {
    const int t = it * 4096 + blockIdx.x * 2 + half;
    const int r0 = sidx[2 * t + 0];
    const int r1 = sidx[2 * t + 1];
    short8 a = *(const short8*)&ye[(size_t)r0 * H + r * 8];
    short8 b = *(const short8*)&ye[(size_t)r1 * H + r * 8];
    float4 s0, s1;
    s0.x = bf2f((u16)a[0]) + bf2f((u16)b[0]);
    s0.y = bf2f((u16)a[1]) + bf2f((u16)b[1]);
    s0.z = bf2f((u16)a[2]) + bf2f((u16)b[2]);
    s0.w = bf2f((u16)a[3]) + bf2f((u16)b[3]);
    s1.x = bf2f((u16)a[4]) + bf2f((u16)b[4]);
    s1.y = bf2f((u16)a[5]) + bf2f((u16)b[5]);
    s1.z = bf2f((u16)a[6]) + bf2f((u16)b[6]);
    s1.w = bf2f((u16)a[7]) + bf2f((u16)b[7]);
    float4* orow = (float4*)(out + (size_t)t * H);
    orow[r * 2 + 0] = s0;
    orow[r * 2 + 1] = s1;
  }
}

extern "C" void kernel_launch(void* const* d_in, const int* in_sizes, int n_in,
                              void* d_out, int out_size, void* d_ws, size_t ws_size,
                              hipStream_t stream) {
  (void)in_sizes; (void)n_in; (void)out_size; (void)ws_size;
  const float* x    = (const float*)d_in[0];
  const float* w0   = (const float*)d_in[1];
  const float* w1   = (const float*)d_in[2];
  const int*   sidx = (const int*)d_in[3];
  float* out = (float*)d_out;

  // workspace layout (168 MB used):
  //   disp: dispatched bf16 [M][H]          33.6 MB @ 0   (aliased as ye)
  //   mid : gelu(x@W0) bf16 [E][CAP][FFN]  134 MB  @ 64 MB
  char* ws = (char*)d_ws;
  const size_t MB = 1024ull * 1024;
  u16* disp = (u16*)ws;
  u16* mid  = (u16*)(ws + 64 * MB);
  u16* ye   = disp;  // disp dead after gemm0

  // 1) scatter + fp32->bf16 cast
  scatter_kernel<<<2048, 256, 0, stream>>>(x, sidx, disp);
  // 2) mid = gelu(disp @ w0), w0 native [E][H][FFN] fp32
  gemm_native_kernel<true><<<4096, 256, 0, stream>>>(
      disp, w0, mid, CAP, FFN, H, CAP / 128);
  // 3) ye = mid @ w1, w1 native [E][FFN][H] fp32
  gemm_native_kernel<false><<<1024, 256, 0, stream>>>(
      mid, w1, ye, CAP, H, FFN, CAP / 128);
  // 4) out[t] = ye[s0] + ye[s1]
  gather_sum_kernel<<<2048, 256, 0, stream>>>(ye, sidx, out);
}